// Round 2
// baseline (166.331 us; speedup 1.0000x reference)
//
#include <hip/hip_runtime.h>

#define BATCH 4096
#define FEATURE_DIM 256
#define NUM_CLASSES 131072
#define CLAMP_MIN 1e-12f
#define CLAMP_MAX 1e12f
#define ROWS_PER_BLOCK 4
#define GRID_MAIN (BATCH / ROWS_PER_BLOCK)   // 1024 blocks

__global__ __launch_bounds__(256) void center_loss_partial_kernel(
        const float* __restrict__ inputs,
        const int* __restrict__ targets,
        const float* __restrict__ center,
        float* __restrict__ partial) {
    __shared__ float wave_sum[4];

    const int wave = threadIdx.x >> 6;   // 0..3
    const int lane = threadIdx.x & 63;   // 0..63
    const int row  = (blockIdx.x << 2) + wave;   // grid = BATCH/4 exactly

    const int tgt = targets[row];        // wave-uniform broadcast load

    // 64 lanes x float4 = 256 floats = one full row, coalesced 1KB segments
    const float4* in4 = reinterpret_cast<const float4*>(inputs + (size_t)row * FEATURE_DIM);
    const float4* ct4 = reinterpret_cast<const float4*>(center + (size_t)tgt * FEATURE_DIM);

    const float4 a = in4[lane];
    const float4 b = ct4[lane];

    const float dx = a.x - b.x;
    const float dy = a.y - b.y;
    const float dz = a.z - b.z;
    const float dw = a.w - b.w;
    float s = dx * dx + dy * dy + dz * dz + dw * dw;

    // wave-64 butterfly reduce
    #pragma unroll
    for (int off = 32; off > 0; off >>= 1) {
        s += __shfl_xor(s, off, 64);
    }

    if (lane == 0) {
        float dist = sqrtf(s);
        dist = fminf(fmaxf(dist, CLAMP_MIN), CLAMP_MAX);
        wave_sum[wave] = dist;
    }
    __syncthreads();

    if (threadIdx.x == 0) {
        // one partial per block; every slot written every launch (ws re-poisoned)
        partial[blockIdx.x] = wave_sum[0] + wave_sum[1] + wave_sum[2] + wave_sum[3];
    }
}

__global__ __launch_bounds__(256) void final_reduce_kernel(
        const float* __restrict__ partial,
        float* __restrict__ out) {
    __shared__ float wave_sum[4];

    const int wave = threadIdx.x >> 6;
    const int lane = threadIdx.x & 63;

    // 256 threads x 4 partials = 1024
    float s = 0.0f;
    #pragma unroll
    for (int i = 0; i < GRID_MAIN / 256; ++i) {
        s += partial[threadIdx.x + i * 256];
    }

    #pragma unroll
    for (int off = 32; off > 0; off >>= 1) {
        s += __shfl_xor(s, off, 64);
    }

    if (lane == 0) wave_sum[wave] = s;
    __syncthreads();

    if (threadIdx.x == 0) {
        float total = wave_sum[0] + wave_sum[1] + wave_sum[2] + wave_sum[3];
        out[0] = total * (1.0f / BATCH)
               + (float)((double)(NUM_CLASSES - 1) * 1e-12);  // clamp constant
    }
}

extern "C" void kernel_launch(void* const* d_in, const int* in_sizes, int n_in,
                              void* d_out, int out_size, void* d_ws, size_t ws_size,
                              hipStream_t stream) {
    const float* inputs  = (const float*)d_in[0];
    const int*   targets = (const int*)d_in[1];
    const float* center  = (const float*)d_in[2];
    float* out     = (float*)d_out;
    float* partial = (float*)d_ws;   // GRID_MAIN floats = 4 KB scratch

    center_loss_partial_kernel<<<GRID_MAIN, 256, 0, stream>>>(inputs, targets, center, partial);
    final_reduce_kernel<<<1, 256, 0, stream>>>(partial, out);
}